// Round 5
// baseline (1647.634 us; speedup 1.0000x reference)
//
#include <hip/hip_runtime.h>
#include <hip/hip_fp16.h>

typedef _Float16 half8 __attribute__((ext_vector_type(8)));
typedef float floatx4 __attribute__((ext_vector_type(4)));

// workspace layout
// h exchange: [parity][group][dim][2] ulong, each = {tag16, hb_lo16, hb_hi16, 0}
#define HBUF_BYTES (2ull * 16 * 1024 * 2 * 8)   // 512 KB
#define XP_OFF     HBUF_BYTES
#define XP_BYTES   (512ull * 64 * 1024 * 2)     // x_proj f16 [t][b][dim] = 64 MB

union hbits { _Float16 f; unsigned short s; };

__device__ inline half8 cvt8(const float4 a, const float4 b) {
    half8 r;
    r[0] = (_Float16)a.x; r[1] = (_Float16)a.y; r[2] = (_Float16)a.z; r[3] = (_Float16)a.w;
    r[4] = (_Float16)b.x; r[5] = (_Float16)b.y; r[6] = (_Float16)b.z; r[7] = (_Float16)b.w;
    return r;
}

// ---------------------------------------------------------------------------
// Phase A: x_proj[t][b][n] = sum_k emb[src[b][t]][k] * W_xh[n][k] + b_xh[n]
// (unchanged — ~300 us, becomes the target once phase B is < ~0.5 ms)
// ---------------------------------------------------------------------------
__global__ __launch_bounds__(256) void xproj_kernel(
    const int* __restrict__ src, const float* __restrict__ emb,
    const float* __restrict__ Wxh, const float* __restrict__ bxh,
    _Float16* __restrict__ xp)
{
    __shared__ _Float16 As[128][40];
    __shared__ _Float16 Bs[128][40];

    const int tid  = threadIdx.x;
    const int lane = tid & 63;
    const int w    = tid >> 6;
    const int m15  = lane & 15;
    const int quad = lane >> 4;
    const int bid  = blockIdx.x;
    const int bn   = bid & 7;
    const int bm   = bid >> 3;
    const int m0   = bm * 128, n0 = bn * 128;
    const int wm   = w & 1, wn = w >> 1;

    const int  srow = tid >> 1;
    const int  scol = (tid & 1) * 16;
    const long arow = (long)src[m0 + srow] * 1024;
    const float* abase = emb + arow + scol;
    const float* bbase = Wxh + (long)(n0 + srow) * 1024 + scol;

    floatx4 zero4 = {0.f, 0.f, 0.f, 0.f};
    floatx4 acc[4][4];
#pragma unroll
    for (int mt = 0; mt < 4; mt++)
#pragma unroll
        for (int nt = 0; nt < 4; nt++) acc[mt][nt] = zero4;

    for (int k0 = 0; k0 < 1024; k0 += 32) {
        __syncthreads();
        float4 a0 = *(const float4*)(abase + k0);
        float4 a1 = *(const float4*)(abase + k0 + 4);
        float4 a2 = *(const float4*)(abase + k0 + 8);
        float4 a3 = *(const float4*)(abase + k0 + 12);
        float4 b0 = *(const float4*)(bbase + k0);
        float4 b1 = *(const float4*)(bbase + k0 + 4);
        float4 b2 = *(const float4*)(bbase + k0 + 8);
        float4 b3 = *(const float4*)(bbase + k0 + 12);
        *(half8*)&As[srow][scol]     = cvt8(a0, a1);
        *(half8*)&As[srow][scol + 8] = cvt8(a2, a3);
        *(half8*)&Bs[srow][scol]     = cvt8(b0, b1);
        *(half8*)&Bs[srow][scol + 8] = cvt8(b2, b3);
        __syncthreads();

        half8 af[4], bf[4];
#pragma unroll
        for (int mt = 0; mt < 4; mt++)
            af[mt] = *(const half8*)&As[wm * 64 + mt * 16 + m15][quad * 8];
#pragma unroll
        for (int nt = 0; nt < 4; nt++)
            bf[nt] = *(const half8*)&Bs[wn * 64 + nt * 16 + m15][quad * 8];
#pragma unroll
        for (int mt = 0; mt < 4; mt++)
#pragma unroll
            for (int nt = 0; nt < 4; nt++)
                acc[mt][nt] = __builtin_amdgcn_mfma_f32_16x16x32_f16(
                    af[mt], bf[nt], acc[mt][nt], 0, 0, 0);
    }

#pragma unroll
    for (int nt = 0; nt < 4; nt++) {
        const int n = n0 + wn * 64 + nt * 16 + m15;
        const float bias = bxh[n];
#pragma unroll
        for (int mt = 0; mt < 4; mt++) {
            const int mrow = m0 + wm * 64 + mt * 16 + quad * 4;
#pragma unroll
            for (int r = 0; r < 4; r++) {
                const int m = mrow + r;
                const int b = m >> 9;
                const int t = m & 511;
                xp[((long)t * 64 + b) * 1024 + n] = (_Float16)(acc[mt][nt][r] + bias);
            }
        }
    }
}

// ---------------------------------------------------------------------------
// Phase B: persistent recurrence, plain launch (256 WGs, 1 WG/CU guaranteed).
// R5 SYNC: tag-in-data. Each 8B word = {tag16, 2 x f16 h}. The 8B atomic
// store is indivisible => tag match implies payload valid. No flags, no
// fences, no vmcnt drain before publish. ONE far-point round trip per step.
// Parity double-buffer retained: member at step t has observed tag t on all
// dims => all peers finished reading tag t-1 => overwriting parity (t+1)&1
// (which holds tag t-1) is safe. 2-deep pipeline invariant.
// ---------------------------------------------------------------------------
__global__ __launch_bounds__(256, 1) void rnn_kernel(
    const float* __restrict__ Whh, const _Float16* __restrict__ xp,
    unsigned long long* __restrict__ hb, float* __restrict__ out)
{
    __shared__ _Float16 hstage[16][1032];       // rows 4..15 stay zero (M-pad)
    __shared__ floatx4  cred[4][4][64];         // [k-slice wave][ntile][lane]

    const int tid    = threadIdx.x;
    const int lane   = tid & 63;
    const int w      = tid >> 6;
    const int m15    = lane & 15;
    const int quad   = lane >> 4;
    const int wg     = blockIdx.x;
    const int g      = wg & 15;
    const int member = wg >> 4;
    const int b0     = g * 4;

    for (int i = tid; i < 16 * 1032; i += 256) ((_Float16*)hstage)[i] = (_Float16)0.f;

    // W_hh slice -> 128 VGPRs (f16), reused for all 512 steps
    half8 Wf[4][8];
#pragma unroll
    for (int nt = 0; nt < 4; nt++) {
        const float* wrow = Whh + (long)(member * 64 + nt * 16 + m15) * 1024
                                + w * 256 + quad * 8;
#pragma unroll
        for (int kk = 0; kk < 8; kk++) {
            float4 lo = *(const float4*)(wrow + kk * 32);
            float4 hi = *(const float4*)(wrow + kk * 32 + 4);
            Wf[nt][kk] = cvt8(lo, hi);
        }
    }
    __syncthreads();

    const int dim = member * 64 + w * 16 + m15;
    float xv[4] = {0.f, 0.f, 0.f, 0.f};
    if (quad == 0) {
#pragma unroll
        for (int r = 0; r < 4; r++)
            xv[r] = (float)xp[((long)0 * 64 + b0 + r) * 1024 + dim];
    }

    floatx4 zero4 = {0.f, 0.f, 0.f, 0.f};

    for (int t = 0; t < 512; t++) {
        // ---- gather h_t: poll tagged words, one round trip --------------
        // thread tid owns dims 4*tid..4*tid+3 => words 8*tid..8*tid+7
        {
            const unsigned long long* hg =
                hb + (size_t)(t & 1) * 32768 + (size_t)g * 2048 + (size_t)tid * 8;
            const unsigned tagu = (unsigned)t;
            unsigned long long v[8];
#pragma unroll
            for (int j = 0; j < 8; j++)
                v[j] = __hip_atomic_load(hg + j, __ATOMIC_RELAXED,
                                         __HIP_MEMORY_SCOPE_AGENT);
            for (;;) {
                unsigned bad = 0;
#pragma unroll
                for (int j = 0; j < 8; j++)
                    if ((unsigned)(v[j] & 0xffffu) != tagu) bad |= (1u << j);
                if (!bad) break;
#pragma unroll
                for (int j = 0; j < 8; j++)
                    if (bad & (1u << j))
                        v[j] = __hip_atomic_load(hg + j, __ATOMIC_RELAXED,
                                                 __HIP_MEMORY_SCOPE_AGENT);
            }
            // unpack: word e*2+(b>>1) holds dim (4*tid+e), batches (b&1 pair)
#pragma unroll
            for (int b = 0; b < 4; b++) {
                unsigned long long q = 0;
#pragma unroll
                for (int e = 0; e < 4; e++) {
                    unsigned long long x =
                        (v[e * 2 + (b >> 1)] >> (16 + 16 * (b & 1))) & 0xffffu;
                    q |= x << (16 * e);
                }
                *(unsigned long long*)&hstage[b][tid * 4] = q;
            }
        }
        __syncthreads();

        // partial GEMM over this wave's K-slice, 4 n-tiles
        floatx4 pacc[4];
#pragma unroll
        for (int nt = 0; nt < 4; nt++) pacc[nt] = zero4;
#pragma unroll
        for (int kk = 0; kk < 8; kk++) {
            half8 a = *(const half8*)&hstage[m15][w * 256 + kk * 32 + quad * 8];
#pragma unroll
            for (int nt = 0; nt < 4; nt++)
                pacc[nt] = __builtin_amdgcn_mfma_f32_16x16x32_f16(
                    a, Wf[nt][kk], pacc[nt], 0, 0, 0);
        }

        // cross-wave K reduction via LDS; wave w finalizes n-tile w
#pragma unroll
        for (int nt = 0; nt < 4; nt++) cred[w][nt][lane] = pacc[nt];
        __syncthreads();
        floatx4 dsum = cred[0][w][lane];
#pragma unroll
        for (int ww = 1; ww < 4; ww++) dsum += cred[ww][w][lane];

        // epilogue: quad 0 holds batches 0..3; pack 2 tagged words, store.
        if (quad == 0) {
            hbits hv[4];
#pragma unroll
            for (int r = 0; r < 4; r++) {
                float pre  = dsum[r] + xv[r];
                float e    = __expf(2.0f * pre);
                float hval = 1.0f - 2.0f / (e + 1.0f);   // tanh
                hv[r].f = (_Float16)hval;
                if (t == 511) out[(b0 + r) * 1024 + dim] = hval;
            }
            const unsigned long long tag1 = (unsigned long long)(unsigned)(t + 1);
            unsigned long long w0 = tag1 | ((unsigned long long)hv[0].s << 16)
                                         | ((unsigned long long)hv[1].s << 32);
            unsigned long long w1 = tag1 | ((unsigned long long)hv[2].s << 16)
                                         | ((unsigned long long)hv[3].s << 32);
            unsigned long long* hw =
                hb + (size_t)((t + 1) & 1) * 32768 + (size_t)g * 2048
                   + (size_t)dim * 2;
            __hip_atomic_store(hw,     w0, __ATOMIC_RELAXED, __HIP_MEMORY_SCOPE_AGENT);
            __hip_atomic_store(hw + 1, w1, __ATOMIC_RELAXED, __HIP_MEMORY_SCOPE_AGENT);
        }

        // prefetch x_proj for t+1; drains while polling at next step
        if (t < 511 && quad == 0) {
#pragma unroll
            for (int r = 0; r < 4; r++)
                xv[r] = (float)xp[((long)(t + 1) * 64 + b0 + r) * 1024 + dim];
        }
    }
}

extern "C" void kernel_launch(void* const* d_in, const int* in_sizes, int n_in,
                              void* d_out, int out_size, void* d_ws, size_t ws_size,
                              hipStream_t stream) {
    const int*   src = (const int*)d_in[0];
    const float* emb = (const float*)d_in[1];
    const float* Wxh = (const float*)d_in[2];
    const float* bxh = (const float*)d_in[3];
    const float* Whh = (const float*)d_in[4];
    float* out = (float*)d_out;

    char* ws = (char*)d_ws;
    unsigned long long* hb = (unsigned long long*)ws;
    _Float16* xp = (_Float16*)(ws + XP_OFF);

    // zero h exchange buffers: tag 0 == "h_0 ready, value 0" for both parities
    hipMemsetAsync(ws, 0, HBUF_BYTES, stream);

    hipLaunchKernelGGL(xproj_kernel, dim3(2048), dim3(256), 0, stream,
                       src, emb, Wxh, bxh, xp);

    hipLaunchKernelGGL(rnn_kernel, dim3(256), dim3(256), 0, stream,
                       Whh, xp, hb, out);
}